// Round 12
// baseline (146.656 us; speedup 1.0000x reference)
//
#include <hip/hip_runtime.h>
#include <hip/hip_bf16.h>
#include <cstdint>

typedef __bf16 bf16;
typedef __attribute__((ext_vector_type(8))) __bf16 bf16x8;
typedef __attribute__((ext_vector_type(4))) __bf16 bf16x4;
typedef __attribute__((ext_vector_type(4))) float f32x4;

#define CEXP 0.1803368801111244f  // (1/8) * log2(e), folded into Q

// Weight packing: element (co, k) of W^T stored at
//   ((co>>4)*16 + (k>>5)) * 512 + (co&15)*32 + (k&31)
// so one (16co x 32k) MFMA B-frag tile is a contiguous 1KB block; a wave's
// B-frag load (lane(quad,l16) -> l16*32 + quad*8) covers it exactly.

// ---------------- prep_all: x transpose + packed weight transposes -------
// (round-11 verified) z in [0,8): xpose batch z. z==8: Wqkv. z==9: Wout.
__global__ __launch_bounds__(256) void prep_all(const float* __restrict__ x,
                                                const float* __restrict__ Wqkv,
                                                const float* __restrict__ Wout,
                                                bf16* __restrict__ xT,
                                                bf16* __restrict__ WqkvP,
                                                bf16* __restrict__ WoutP) {
  __shared__ bf16 t[32][33];
  const int z = blockIdx.z;
  const int c0 = blockIdx.x * 32, r0 = blockIdx.y * 32;
  const int tx = threadIdx.x, ty = threadIdx.y;

  if (z < 8) {  // x[b][c][n] -> xT[b][n][c]
    const float* src = x + (size_t)z * 512 * 1024;
    bf16* dst = xT + (size_t)z * 1024 * 512;
    if (blockIdx.x >= 32) return;  // block-uniform exit before barrier
#pragma unroll
    for (int i = 0; i < 4; ++i)
      t[ty + i * 8][tx] = (bf16)src[(size_t)(r0 + ty + i * 8) * 1024 + c0 + tx];
    __syncthreads();
#pragma unroll
    for (int i = 0; i < 4; ++i)
      dst[(size_t)(c0 + ty + i * 8) * 512 + r0 + tx] = t[tx][ty + i * 8];
    return;
  }
  // weights: src [512 k][C co] tile at k=r0(32-aligned), co=c0 -> packed
  const float* src;
  bf16* dstp;
  int C;
  if (z == 8) {
    src = Wqkv; dstp = WqkvP; C = 1536;
  } else {
    if (blockIdx.x >= 16) return;
    src = Wout; dstp = WoutP; C = 512;
  }
#pragma unroll
  for (int i = 0; i < 4; ++i)
    t[ty + i * 8][tx] = (bf16)src[(size_t)(r0 + ty + i * 8) * C + c0 + tx];
  __syncthreads();
#pragma unroll
  for (int i = 0; i < 4; ++i) {
    const int co = c0 + ty + i * 8;  // t[tx][ty+i*8] = W[k=r0+tx][co]
    dstp[(size_t)((co >> 4) * 16 + (r0 >> 5)) * 512 + (co & 15) * 32 + tx] =
        t[tx][ty + i * 8];
  }
}

// ---------------- GEMM1: qkv = xT @ Wqkv + b, scatter into Q/K/V --------
// Combined rebuild: round-10's BK=128 A-path (reg-prefetch av[8], 4 k-iters,
// verified) + round-11's direct packed-B reads (verified) at the 64-wide co
// tile. LDS = As only (34.8KB -> comfortable 3 blocks/CU, fixing r10's
// 156.7KB near-limit). 24 LDS ops / 32 MFMA per iter. Same k order =>
// bitwise-identical output.
__global__ __launch_bounds__(256, 3) void gemm_qkv(const bf16* __restrict__ xT,
                                                   const bf16* __restrict__ WqkvP,
                                                   const float* __restrict__ bqkv,
                                                   bf16* __restrict__ Qb,
                                                   bf16* __restrict__ Kb,
                                                   bf16* __restrict__ Vb) {
  __shared__ bf16 As[128 * 136];
  const int b = blockIdx.z;
  const int m0 = blockIdx.y * 128;
  const int co0 = blockIdx.x * 64;
  const int tid = threadIdx.x;
  const int w = tid >> 6, l = tid & 63;
  const int wr = w >> 1, wc = w & 1;
  const int quad = l >> 4, l16 = l & 15;

  const bf16* A = xT + (size_t)b * 1024 * 512;

  f32x4 acc[4][2];
#pragma unroll
  for (int i = 0; i < 4; ++i)
#pragma unroll
    for (int j = 0; j < 2; ++j) acc[i][j] = (f32x4){0.f, 0.f, 0.f, 0.f};

  const int srow = w * 32 + (l >> 3);     // A staging: 128 rows, 8 rows/i
  const int scol = (l & 7) * 8;           // + g*64 col group
  const int lfrag = l16 * 32 + quad * 8;  // lane offset in a 1KB frag tile

  bf16x8 av[8];  // prologue: prefetch A k-tile 0 (128 wide)
#pragma unroll
  for (int g = 0; g < 2; ++g)
#pragma unroll
    for (int i = 0; i < 4; ++i)
      av[g * 4 + i] = *(const bf16x8*)&A[(size_t)(m0 + srow + i * 8) * 512 + g * 64 + scol];

  for (int kk = 0; kk < 4; ++kk) {
    __syncthreads();  // prev iter's As frag reads done (no-op at kk=0)
#pragma unroll
    for (int g = 0; g < 2; ++g)
#pragma unroll
      for (int i = 0; i < 4; ++i)
        *(bf16x8*)&As[(srow + i * 8) * 136 + g * 64 + scol] = av[g * 4 + i];
    __syncthreads();
    if (kk < 3) {  // prefetch next A k-tile; latency hides under MFMA below
      const int k0 = (kk + 1) * 128;
#pragma unroll
      for (int g = 0; g < 2; ++g)
#pragma unroll
        for (int i = 0; i < 4; ++i)
          av[g * 4 + i] = *(const bf16x8*)&A[(size_t)(m0 + srow + i * 8) * 512 + k0 + g * 64 + scol];
    }
    // B-frags direct from packed global (L2-resident, coalesced 1KB/wave)
    bf16x8 bb[4][2];  // [ks][cb]; k index = kk*4 + ks
#pragma unroll
    for (int ks = 0; ks < 4; ++ks)
#pragma unroll
      for (int cb = 0; cb < 2; ++cb)
        bb[ks][cb] = *(const bf16x8*)&WqkvP[(size_t)(((co0 >> 4) + wc * 2 + cb) * 16 +
                                                     kk * 4 + ks) * 512 + lfrag];
#pragma unroll
    for (int ks = 0; ks < 4; ++ks) {
      bf16x8 a[4];
#pragma unroll
      for (int rb = 0; rb < 4; ++rb)
        a[rb] = *(const bf16x8*)&As[(wr * 64 + rb * 16 + l16) * 136 + ks * 32 + quad * 8];
#pragma unroll
      for (int rb = 0; rb < 4; ++rb)
#pragma unroll
        for (int cb = 0; cb < 2; ++cb)
          acc[rb][cb] = __builtin_amdgcn_mfma_f32_16x16x32_bf16(a[rb], bb[ks][cb], acc[rb][cb], 0, 0, 0);
    }
  }

  // epilogue (round-6 verified): co0 64-aligned, 192=3*64 -> h/part uniform
  const int h = co0 / 192;
  const int part = (co0 - h * 192) >> 6;
#pragma unroll
  for (int cb = 0; cb < 2; ++cb) {
    const int dd = wc * 32 + cb * 16 + l16;  // d within the 64-wide part
    const float bias = bqkv[co0 + dd];
    if (part == 2) {  // V: d-major, vector store of 4 consecutive n
      bf16* base = Vb + ((size_t)(b * 8 + h) * 64 + dd) * 1024;
#pragma unroll
      for (int rb = 0; rb < 4; ++rb) {
        const int n = m0 + wr * 64 + rb * 16 + quad * 4;
        f32x4 v = acc[rb][cb];
        bf16x4 ov;
#pragma unroll
        for (int r = 0; r < 4; ++r) ov[r] = (bf16)(v[r] + bias);
        *(bf16x4*)&base[n] = ov;
      }
    } else {  // Q (pre-scaled by CEXP) / K: [bh][n][64]
      const float sc = (part == 0) ? CEXP : 1.0f;
      bf16* dst = (part == 0) ? Qb : Kb;
      bf16* base = dst + ((size_t)(b * 8 + h) * 1024) * 64 + dd;
#pragma unroll
      for (int rb = 0; rb < 4; ++rb) {
        const int n = m0 + wr * 64 + rb * 16 + quad * 4;
        f32x4 v = acc[rb][cb];
#pragma unroll
        for (int r = 0; r < 4; ++r) base[(size_t)(n + r) * 64] = (bf16)((v[r] + bias) * sc);
      }
    }
  }
}

// ---------------- flash attention v6: in-register P, sigma-matched V -----
// (round-3/6 verified: passed at absmax 0.03125 — unchanged)
__global__ __launch_bounds__(256) void attn_k(const bf16* __restrict__ Qb,
                                              const bf16* __restrict__ Kb,
                                              const bf16* __restrict__ Vb,
                                              bf16* __restrict__ Ob) {
  __shared__ bf16 Ks[128 * 72];   // [j][d]
  __shared__ bf16 Vs[64 * 136];   // [d][j]
  const int bh = blockIdx.x;      // bh fastest => head pinned per XCD
  const int b = bh >> 3, h = bh & 7;
  const int q0 = blockIdx.y * 128;
  const int tid = threadIdx.x;
  const int w = tid >> 6, l = tid & 63;
  const int quad = l >> 4, l16 = l & 15;

  const bf16* Qg = Qb + (size_t)bh * 1024 * 64;
  const bf16* Kg = Kb + (size_t)bh * 1024 * 64;
  const bf16* Vg = Vb + (size_t)bh * 64 * 1024;

  bf16x8 qb[2][2];
#pragma unroll
  for (int mt = 0; mt < 2; ++mt)
#pragma unroll
    for (int ks = 0; ks < 2; ++ks)
      qb[mt][ks] = *(const bf16x8*)&Qg[(size_t)(q0 + w * 32 + mt * 16 + l16) * 64 + ks * 32 + quad * 8];

  bf16x8 ones;
#pragma unroll
  for (int e = 0; e < 8; ++e) ones[e] = (bf16)1.0f;

  f32x4 o[2][4], acc_l[2];
#pragma unroll
  for (int mt = 0; mt < 2; ++mt) {
    acc_l[mt] = (f32x4){0.f, 0.f, 0.f, 0.f};
#pragma unroll
    for (int db = 0; db < 4; ++db) o[mt][db] = (f32x4){0.f, 0.f, 0.f, 0.f};
  }

  const int kr = tid >> 1, kc = (tid & 1) * 32;  // K: 128j x 64d
  const int vr = tid >> 2, vc = (tid & 3) * 32;  // V: 64d x 128j

  bf16x8 ka[4], va[4];  // prefetch tile 0
#pragma unroll
  for (int e = 0; e < 4; ++e) {
    ka[e] = *(const bf16x8*)&Kg[(size_t)kr * 64 + kc + e * 8];
    va[e] = *(const bf16x8*)&Vg[(size_t)vr * 1024 + vc + e * 8];
  }

  for (int kv = 0; kv < 8; ++kv) {
    __syncthreads();  // prev iter's Ks/Vs reads done
#pragma unroll
    for (int e = 0; e < 4; ++e) {
      *(bf16x8*)&Ks[kr * 72 + kc + e * 8] = ka[e];
      *(bf16x8*)&Vs[vr * 136 + vc + e * 8] = va[e];
    }
    __syncthreads();
    if (kv < 7) {  // prefetch next tile
      const int j0 = (kv + 1) * 128;
#pragma unroll
      for (int e = 0; e < 4; ++e) {
        ka[e] = *(const bf16x8*)&Kg[(size_t)(j0 + kr) * 64 + kc + e * 8];
        va[e] = *(const bf16x8*)&Vg[(size_t)vr * 1024 + j0 + vc + e * 8];
      }
    }

    // QK^T: s[mt][jb]; lane (quad,l16) holds j = jb*16 + quad*4 + rr for its
    // own m = w*32 + mt*16 + l16 (all 128 j live in this wave).
    f32x4 s[2][8];
#pragma unroll
    for (int mt = 0; mt < 2; ++mt)
#pragma unroll
      for (int jb = 0; jb < 8; ++jb) s[mt][jb] = (f32x4){0.f, 0.f, 0.f, 0.f};
#pragma unroll
    for (int ks = 0; ks < 2; ++ks) {
      bf16x8 kaf[8];
#pragma unroll
      for (int jb = 0; jb < 8; ++jb)
        kaf[jb] = *(const bf16x8*)&Ks[(jb * 16 + l16) * 72 + ks * 32 + quad * 8];
#pragma unroll
      for (int jb = 0; jb < 8; ++jb)
#pragma unroll
        for (int mt = 0; mt < 2; ++mt)
          s[mt][jb] = __builtin_amdgcn_mfma_f32_16x16x32_bf16(kaf[jb], qb[mt][ks], s[mt][jb], 0, 0, 0);
    }

    // PV with P kept in the lanes that computed it.
    // ap slot mapping within 32-j block: slot 8q+e -> j = 4q+(e&3)+16*(e>>2).
    // bv is read with the same sigma: e<4 from j=kj*32+4q+e, e>=4 from +16.
#pragma unroll
    for (int kj = 0; kj < 4; ++kj) {
      bf16x8 bv[4];
#pragma unroll
      for (int db = 0; db < 4; ++db) {
        const bf16x4 lo = *(const bf16x4*)&Vs[(db * 16 + l16) * 136 + kj * 32 + quad * 4];
        const bf16x4 hi = *(const bf16x4*)&Vs[(db * 16 + l16) * 136 + kj * 32 + 16 + quad * 4];
#pragma unroll
        for (int e = 0; e < 4; ++e) {
          bv[db][e] = lo[e];
          bv[db][4 + e] = hi[e];
        }
      }
#pragma unroll
      for (int mt = 0; mt < 2; ++mt) {
        bf16x8 ap;
#pragma unroll
        for (int rr = 0; rr < 4; ++rr) {
          ap[rr] = (bf16)__builtin_amdgcn_exp2f(s[mt][2 * kj][rr]);
          ap[4 + rr] = (bf16)__builtin_amdgcn_exp2f(s[mt][2 * kj + 1][rr]);
        }
        acc_l[mt] = __builtin_amdgcn_mfma_f32_16x16x32_bf16(ap, ones, acc_l[mt], 0, 0, 0);
#pragma unroll
        for (int db = 0; db < 4; ++db)
          o[mt][db] = __builtin_amdgcn_mfma_f32_16x16x32_bf16(ap, bv[db], o[mt][db], 0, 0, 0);
      }
    }
  }

  // epilogue: O /= l, write [b][n][h*64+d]
  bf16* Og = Ob + (size_t)b * 1024 * 512 + h * 64;
#pragma unroll
  for (int mt = 0; mt < 2; ++mt) {
    f32x4 inv;
#pragma unroll
    for (int rr = 0; rr < 4; ++rr) inv[rr] = 1.0f / acc_l[mt][rr];
#pragma unroll
    for (int db = 0; db < 4; ++db)
#pragma unroll
      for (int rr = 0; rr < 4; ++rr) {
        const int n = q0 + w * 32 + mt * 16 + quad * 4 + rr;
        Og[(size_t)n * 512 + db * 16 + l16] = (bf16)(o[mt][db][rr] * inv[rr]);
      }
  }
}

// ---------------- GEMM2: out = (O @ Wout + b + x)^T ---------------------
// (round-11 verified: A staged in LDS, B-frags direct from packed global)
__global__ __launch_bounds__(256, 3) void gemm_out(const bf16* __restrict__ Ob,
                                                   const bf16* __restrict__ WoutP,
                                                   const float* __restrict__ bout,
                                                   const float* __restrict__ x,
                                                   float* __restrict__ out) {
  __shared__ bf16 As[128 * 72];
  const int b = blockIdx.z;
  const int m0 = blockIdx.y * 128;
  const int co0 = blockIdx.x * 64;
  const int tid = threadIdx.x;
  const int w = tid >> 6, l = tid & 63;
  const int wr = w >> 1, wc = w & 1;
  const int quad = l >> 4, l16 = l & 15;

  const bf16* A = Ob + (size_t)b * 1024 * 512;

  f32x4 acc[4][2];
#pragma unroll
  for (int i = 0; i < 4; ++i)
#pragma unroll
    for (int j = 0; j < 2; ++j) acc[i][j] = (f32x4){0.f, 0.f, 0.f, 0.f};

  const int srow = w * 32 + (l >> 3);
  const int scol = (l & 7) * 8;
  const int lfrag = l16 * 32 + quad * 8;

  bf16x8 av[4];
#pragma unroll
  for (int i = 0; i < 4; ++i)
    av[i] = *(const bf16x8*)&A[(size_t)(m0 + srow + i * 8) * 512 + scol];

  for (int kk = 0; kk < 8; ++kk) {
    __syncthreads();
#pragma unroll
    for (int i = 0; i < 4; ++i)
      *(bf16x8*)&As[(srow + i * 8) * 72 + scol] = av[i];
    __syncthreads();
    if (kk < 7) {
      const int k0 = (kk + 1) * 64;
#pragma unroll
      for (int i = 0; i < 4; ++i)
        av[i] = *(const bf16x8*)&A[(size_t)(m0 + srow + i * 8) * 512 + k0 + scol];
    }
    bf16x8 bb[2][2];
#pragma unroll
    for (int ks = 0; ks < 2; ++ks)
#pragma unroll
      for (int cb = 0; cb < 2; ++cb)
        bb[ks][cb] = *(const bf16x8*)&WoutP[(size_t)(((co0 >> 4) + wc * 2 + cb) * 16 +
                                                     kk * 2 + ks) * 512 + lfrag];
#pragma unroll
    for (int ks = 0; ks < 2; ++ks) {
      bf16x8 a[4];
#pragma unroll
      for (int rb = 0; rb < 4; ++rb)
        a[rb] = *(const bf16x8*)&As[(wr * 64 + rb * 16 + l16) * 72 + ks * 32 + quad * 8];
#pragma unroll
      for (int rb = 0; rb < 4; ++rb)
#pragma unroll
        for (int cb = 0; cb < 2; ++cb)
          acc[rb][cb] = __builtin_amdgcn_mfma_f32_16x16x32_bf16(a[rb], bb[ks][cb], acc[rb][cb], 0, 0, 0);
    }
  }

#pragma unroll
  for (int cb = 0; cb < 2; ++cb) {
    const int c = co0 + wc * 32 + cb * 16 + l16;
    const float bias = bout[c];
#pragma unroll
    for (int rb = 0; rb < 4; ++rb) {
      const int n = m0 + wr * 64 + rb * 16 + quad * 4;
      const size_t off = ((size_t)b * 512 + c) * 1024 + n;
      f32x4 res = *(const f32x4*)&x[off];
      f32x4 v = acc[rb][cb];
      f32x4 ov;
#pragma unroll
      for (int r = 0; r < 4; ++r) ov[r] = v[r] + bias + res[r];
      *(f32x4*)&out[off] = ov;
    }
  }
}

extern "C" void kernel_launch(void* const* d_in, const int* in_sizes, int n_in,
                              void* d_out, int out_size, void* d_ws, size_t ws_size,
                              hipStream_t stream) {
  const float* x = (const float*)d_in[0];     // [8][512][1024] fp32
  const float* Wqkv = (const float*)d_in[1];  // [512][1536]
  const float* bqkv = (const float*)d_in[2];  // [1536]
  const float* Wout = (const float*)d_in[3];  // [512][512]
  const float* bout = (const float*)d_in[4];  // [512]
  float* out = (float*)d_out;                 // [8][512][1024]
  char* ws = (char*)d_ws;

  const size_t MB = 1024 * 1024;
  bf16* xT = (bf16*)(ws);             // 8 MB [8][1024][512] bf16
  bf16* Ob = xT;                      // alias: xT dead after gemm_qkv
  bf16* Qbuf = (bf16*)(ws + 8 * MB);  // 8 MB [64][1024][64] (pre-scaled)
  bf16* Kbuf = (bf16*)(ws + 16 * MB); // 8 MB [64][1024][64]
  bf16* Vbuf = (bf16*)(ws + 24 * MB); // 8 MB [64][64][1024] d-major
  bf16* WqkvP = (bf16*)(ws + 32 * MB);            // 1.5 MB packed frag tiles
  bf16* WoutP = (bf16*)(ws + 32 * MB + 1572864);  // 0.5 MB packed frag tiles
  if (ws_size < 32 * MB + 1572864 + 524288) return;

  prep_all<<<dim3(48, 16, 10), dim3(32, 8), 0, stream>>>(x, Wqkv, Wout, xT, WqkvP, WoutP);
  gemm_qkv<<<dim3(24, 8, 8), 256, 0, stream>>>(xT, WqkvP, bqkv, Qbuf, Kbuf, Vbuf);
  attn_k<<<dim3(64, 8), 256, 0, stream>>>(Qbuf, Kbuf, Vbuf, Ob);
  gemm_out<<<dim3(8, 8, 8), 256, 0, stream>>>(Ob, WoutP, bout, x, out);
}

// Round 13
// 141.231 us; speedup vs baseline: 1.0384x; 1.0384x over previous
//
#include <hip/hip_runtime.h>
#include <hip/hip_bf16.h>
#include <cstdint>

typedef __bf16 bf16;
typedef __attribute__((ext_vector_type(8))) __bf16 bf16x8;
typedef __attribute__((ext_vector_type(4))) __bf16 bf16x4;
typedef __attribute__((ext_vector_type(4))) float f32x4;

#define CEXP 0.1803368801111244f  // (1/8) * log2(e), folded into Q

// ---------------- prep_all: x transpose + weight transposes, one launch ---
// z in [0,8): xpose batch z. z==8: Wqkv. z==9: Wout.
__global__ __launch_bounds__(256) void prep_all(const float* __restrict__ x,
                                                const float* __restrict__ Wqkv,
                                                const float* __restrict__ Wout,
                                                bf16* __restrict__ xT,
                                                bf16* __restrict__ WqkvT,
                                                bf16* __restrict__ WoutT) {
  __shared__ bf16 t[32][33];
  const int z = blockIdx.z;
  const float* src;
  bf16* dst;
  int C;  // src row length; dst row length is always 512
  if (z < 8) {
    if (blockIdx.x >= 32) return;  // block-uniform exit before barrier
    src = x + (size_t)z * 512 * 1024;
    dst = xT + (size_t)z * 1024 * 512;
    C = 1024;
  } else if (z == 8) {
    src = Wqkv; dst = WqkvT; C = 1536;
  } else {
    if (blockIdx.x >= 16) return;
    src = Wout; dst = WoutT; C = 512;
  }
  const int c0 = blockIdx.x * 32, r0 = blockIdx.y * 32;
  const int tx = threadIdx.x, ty = threadIdx.y;
#pragma unroll
  for (int i = 0; i < 4; ++i)
    t[ty + i * 8][tx] = (bf16)src[(size_t)(r0 + ty + i * 8) * C + c0 + tx];
  __syncthreads();
#pragma unroll
  for (int i = 0; i < 4; ++i)
    dst[(size_t)(c0 + ty + i * 8) * 512 + r0 + tx] = t[tx][ty + i * 8];
}

// ---------------- GEMM1: qkv = xT @ Wqkv + b, scatter into Q/K/V --------
// Round-10 verified best (141.4us total): BK=128 (4 k-iters) + register
// prefetch across k-iters (sync -> LDS-write -> sync -> issue next loads ->
// MFMA). Same k-summation order as the round-0 baseline.
__global__ __launch_bounds__(256, 3) void gemm_qkv(const bf16* __restrict__ xT,
                                                   const bf16* __restrict__ WqkvT,
                                                   const float* __restrict__ bqkv,
                                                   bf16* __restrict__ Qb,
                                                   bf16* __restrict__ Kb,
                                                   bf16* __restrict__ Vb) {
  __shared__ bf16 As[128 * 136];
  __shared__ bf16 Bs[64 * 136];
  const int b = blockIdx.z;
  const int m0 = blockIdx.y * 128;
  const int co0 = blockIdx.x * 64;
  const int tid = threadIdx.x;
  const int w = tid >> 6, l = tid & 63;
  const int wr = w >> 1, wc = w & 1;
  const int quad = l >> 4, l16 = l & 15;

  const bf16* A = xT + (size_t)b * 1024 * 512;

  f32x4 acc[4][2];
#pragma unroll
  for (int i = 0; i < 4; ++i)
#pragma unroll
    for (int j = 0; j < 2; ++j) acc[i][j] = (f32x4){0.f, 0.f, 0.f, 0.f};

  const int srow = w * 32 + (l >> 3);  // A staging: 128 rows, 8 rows/i-step
  const int scol = (l & 7) * 8;        // + g*64 col group
  const int brow = tid >> 2;           // B staging: 64 rows
  const int bcol = (tid & 3) * 16;     // + g*64 col group

  // prologue: prefetch k-tile 0 into registers
  bf16x8 av[8], bv[4];
#pragma unroll
  for (int g = 0; g < 2; ++g) {
#pragma unroll
    for (int i = 0; i < 4; ++i)
      av[g * 4 + i] = *(const bf16x8*)&A[(size_t)(m0 + srow + i * 8) * 512 + g * 64 + scol];
#pragma unroll
    for (int i = 0; i < 2; ++i)
      bv[g * 2 + i] = *(const bf16x8*)&WqkvT[(size_t)(co0 + brow) * 512 + g * 64 + bcol + i * 8];
  }

  for (int kk = 0; kk < 4; ++kk) {
    __syncthreads();  // prev iter's LDS frag reads done (no-op at kk=0)
#pragma unroll
    for (int g = 0; g < 2; ++g) {
#pragma unroll
      for (int i = 0; i < 4; ++i)
        *(bf16x8*)&As[(srow + i * 8) * 136 + g * 64 + scol] = av[g * 4 + i];
#pragma unroll
      for (int i = 0; i < 2; ++i)
        *(bf16x8*)&Bs[brow * 136 + g * 64 + bcol + i * 8] = bv[g * 2 + i];
    }
    __syncthreads();
    if (kk < 3) {  // issue next k-tile loads; latency hides under MFMA below
      const int k0 = (kk + 1) * 128;
#pragma unroll
      for (int g = 0; g < 2; ++g) {
#pragma unroll
        for (int i = 0; i < 4; ++i)
          av[g * 4 + i] = *(const bf16x8*)&A[(size_t)(m0 + srow + i * 8) * 512 + k0 + g * 64 + scol];
#pragma unroll
        for (int i = 0; i < 2; ++i)
          bv[g * 2 + i] = *(const bf16x8*)&WqkvT[(size_t)(co0 + brow) * 512 + k0 + g * 64 + bcol + i * 8];
      }
    }
#pragma unroll
    for (int ks = 0; ks < 4; ++ks) {
      bf16x8 a[4], bb[2];
#pragma unroll
      for (int rb = 0; rb < 4; ++rb)
        a[rb] = *(const bf16x8*)&As[(wr * 64 + rb * 16 + l16) * 136 + ks * 32 + quad * 8];
#pragma unroll
      for (int cb = 0; cb < 2; ++cb)
        bb[cb] = *(const bf16x8*)&Bs[(wc * 32 + cb * 16 + l16) * 136 + ks * 32 + quad * 8];
#pragma unroll
      for (int rb = 0; rb < 4; ++rb)
#pragma unroll
        for (int cb = 0; cb < 2; ++cb)
          acc[rb][cb] = __builtin_amdgcn_mfma_f32_16x16x32_bf16(a[rb], bb[cb], acc[rb][cb], 0, 0, 0);
    }
  }

  // epilogue: co0 is 64-aligned and 192 = 3*64 -> head & part are uniform.
  const int h = co0 / 192;
  const int part = (co0 - h * 192) >> 6;
#pragma unroll
  for (int cb = 0; cb < 2; ++cb) {
    const int dd = wc * 32 + cb * 16 + l16;  // d within the 64-wide part
    const float bias = bqkv[co0 + dd];
    if (part == 2) {  // V: d-major, vector store of 4 consecutive n
      bf16* base = Vb + ((size_t)(b * 8 + h) * 64 + dd) * 1024;
#pragma unroll
      for (int rb = 0; rb < 4; ++rb) {
        const int n = m0 + wr * 64 + rb * 16 + quad * 4;
        f32x4 v = acc[rb][cb];
        bf16x4 ov;
#pragma unroll
        for (int r = 0; r < 4; ++r) ov[r] = (bf16)(v[r] + bias);
        *(bf16x4*)&base[n] = ov;
      }
    } else {  // Q (pre-scaled by CEXP) / K: [bh][n][64]
      const float sc = (part == 0) ? CEXP : 1.0f;
      bf16* dst = (part == 0) ? Qb : Kb;
      bf16* base = dst + ((size_t)(b * 8 + h) * 1024) * 64 + dd;
#pragma unroll
      for (int rb = 0; rb < 4; ++rb) {
        const int n = m0 + wr * 64 + rb * 16 + quad * 4;
        f32x4 v = acc[rb][cb];
#pragma unroll
        for (int r = 0; r < 4; ++r) base[(size_t)(n + r) * 64] = (bf16)((v[r] + bias) * sc);
      }
    }
  }
}

// ---------------- flash attention v6: in-register P, sigma-matched V -----
// (round-3/6 verified: passed at absmax 0.03125 — unchanged)
__global__ __launch_bounds__(256) void attn_k(const bf16* __restrict__ Qb,
                                              const bf16* __restrict__ Kb,
                                              const bf16* __restrict__ Vb,
                                              bf16* __restrict__ Ob) {
  __shared__ bf16 Ks[128 * 72];   // [j][d]
  __shared__ bf16 Vs[64 * 136];   // [d][j]
  const int bh = blockIdx.x;      // bh fastest => head pinned per XCD
  const int b = bh >> 3, h = bh & 7;
  const int q0 = blockIdx.y * 128;
  const int tid = threadIdx.x;
  const int w = tid >> 6, l = tid & 63;
  const int quad = l >> 4, l16 = l & 15;

  const bf16* Qg = Qb + (size_t)bh * 1024 * 64;
  const bf16* Kg = Kb + (size_t)bh * 1024 * 64;
  const bf16* Vg = Vb + (size_t)bh * 64 * 1024;

  // Q B-fragments straight from global: m = q0 + w*32 + mt*16 + l16
  bf16x8 qb[2][2];
#pragma unroll
  for (int mt = 0; mt < 2; ++mt)
#pragma unroll
    for (int ks = 0; ks < 2; ++ks)
      qb[mt][ks] = *(const bf16x8*)&Qg[(size_t)(q0 + w * 32 + mt * 16 + l16) * 64 + ks * 32 + quad * 8];

  bf16x8 ones;
#pragma unroll
  for (int e = 0; e < 8; ++e) ones[e] = (bf16)1.0f;

  f32x4 o[2][4], acc_l[2];
#pragma unroll
  for (int mt = 0; mt < 2; ++mt) {
    acc_l[mt] = (f32x4){0.f, 0.f, 0.f, 0.f};
#pragma unroll
    for (int db = 0; db < 4; ++db) o[mt][db] = (f32x4){0.f, 0.f, 0.f, 0.f};
  }

  const int kr = tid >> 1, kc = (tid & 1) * 32;  // K: 128j x 64d
  const int vr = tid >> 2, vc = (tid & 3) * 32;  // V: 64d x 128j

  bf16x8 ka[4], va[4];  // prefetch tile 0
#pragma unroll
  for (int e = 0; e < 4; ++e) {
    ka[e] = *(const bf16x8*)&Kg[(size_t)kr * 64 + kc + e * 8];
    va[e] = *(const bf16x8*)&Vg[(size_t)vr * 1024 + vc + e * 8];
  }

  for (int kv = 0; kv < 8; ++kv) {
    __syncthreads();  // prev iter's Ks/Vs reads done
#pragma unroll
    for (int e = 0; e < 4; ++e) {
      *(bf16x8*)&Ks[kr * 72 + kc + e * 8] = ka[e];
      *(bf16x8*)&Vs[vr * 136 + vc + e * 8] = va[e];
    }
    __syncthreads();
    if (kv < 7) {  // prefetch next tile
      const int j0 = (kv + 1) * 128;
#pragma unroll
      for (int e = 0; e < 4; ++e) {
        ka[e] = *(const bf16x8*)&Kg[(size_t)(j0 + kr) * 64 + kc + e * 8];
        va[e] = *(const bf16x8*)&Vg[(size_t)vr * 1024 + j0 + vc + e * 8];
      }
    }

    // QK^T: s[mt][jb]; lane (quad,l16) holds j = jb*16 + quad*4 + rr for its
    // own m = w*32 + mt*16 + l16 (all 128 j live in this wave).
    f32x4 s[2][8];
#pragma unroll
    for (int mt = 0; mt < 2; ++mt)
#pragma unroll
      for (int jb = 0; jb < 8; ++jb) s[mt][jb] = (f32x4){0.f, 0.f, 0.f, 0.f};
#pragma unroll
    for (int ks = 0; ks < 2; ++ks) {
      bf16x8 kaf[8];
#pragma unroll
      for (int jb = 0; jb < 8; ++jb)
        kaf[jb] = *(const bf16x8*)&Ks[(jb * 16 + l16) * 72 + ks * 32 + quad * 8];
#pragma unroll
      for (int jb = 0; jb < 8; ++jb)
#pragma unroll
        for (int mt = 0; mt < 2; ++mt)
          s[mt][jb] = __builtin_amdgcn_mfma_f32_16x16x32_bf16(kaf[jb], qb[mt][ks], s[mt][jb], 0, 0, 0);
    }

    // PV with P kept in the lanes that computed it.
    // ap slot mapping within 32-j block: slot 8q+e -> j = 4q+(e&3)+16*(e>>2).
    // bv is read with the same sigma: e<4 from j=kj*32+4q+e, e>=4 from +16.
#pragma unroll
    for (int kj = 0; kj < 4; ++kj) {
      bf16x8 bv[4];
#pragma unroll
      for (int db = 0; db < 4; ++db) {
        const bf16x4 lo = *(const bf16x4*)&Vs[(db * 16 + l16) * 136 + kj * 32 + quad * 4];
        const bf16x4 hi = *(const bf16x4*)&Vs[(db * 16 + l16) * 136 + kj * 32 + 16 + quad * 4];
#pragma unroll
        for (int e = 0; e < 4; ++e) {
          bv[db][e] = lo[e];
          bv[db][4 + e] = hi[e];
        }
      }
#pragma unroll
      for (int mt = 0; mt < 2; ++mt) {
        bf16x8 ap;
#pragma unroll
        for (int rr = 0; rr < 4; ++rr) {
          ap[rr] = (bf16)__builtin_amdgcn_exp2f(s[mt][2 * kj][rr]);
          ap[4 + rr] = (bf16)__builtin_amdgcn_exp2f(s[mt][2 * kj + 1][rr]);
        }
        acc_l[mt] = __builtin_amdgcn_mfma_f32_16x16x32_bf16(ap, ones, acc_l[mt], 0, 0, 0);
#pragma unroll
        for (int db = 0; db < 4; ++db)
          o[mt][db] = __builtin_amdgcn_mfma_f32_16x16x32_bf16(ap, bv[db], o[mt][db], 0, 0, 0);
      }
    }
  }

  // epilogue: O /= l, write [b][n][h*64+d]
  bf16* Og = Ob + (size_t)b * 1024 * 512 + h * 64;
#pragma unroll
  for (int mt = 0; mt < 2; ++mt) {
    f32x4 inv;
#pragma unroll
    for (int rr = 0; rr < 4; ++rr) inv[rr] = 1.0f / acc_l[mt][rr];
#pragma unroll
    for (int db = 0; db < 4; ++db)
#pragma unroll
      for (int rr = 0; rr < 4; ++rr) {
        const int n = q0 + w * 32 + mt * 16 + quad * 4 + rr;
        Og[(size_t)n * 512 + db * 16 + l16] = (bf16)(o[mt][db][rr] * inv[rr]);
      }
  }
}

// ---------------- GEMM2: out = (O @ Wout + b + x)^T (round-6 body) -------
__global__ __launch_bounds__(256, 3) void gemm_out(const bf16* __restrict__ Ob,
                                                   const bf16* __restrict__ WoutT,
                                                   const float* __restrict__ bout,
                                                   const float* __restrict__ x,
                                                   float* __restrict__ out) {
  __shared__ bf16 As[128 * 72];
  __shared__ bf16 Bs[64 * 72];
  const int b = blockIdx.z;
  const int m0 = blockIdx.y * 128;
  const int co0 = blockIdx.x * 64;
  const int tid = threadIdx.x;
  const int w = tid >> 6, l = tid & 63;
  const int wr = w >> 1, wc = w & 1;
  const int quad = l >> 4, l16 = l & 15;

  const bf16* A = Ob + (size_t)b * 1024 * 512;

  f32x4 acc[4][2];
#pragma unroll
  for (int i = 0; i < 4; ++i)
#pragma unroll
    for (int j = 0; j < 2; ++j) acc[i][j] = (f32x4){0.f, 0.f, 0.f, 0.f};

  const int srow = w * 32 + (l >> 3);
  const int scol = (l & 7) * 8;
  const int brow = tid >> 2;
  const int bcol = (tid & 3) * 16;

  for (int kk = 0; kk < 8; ++kk) {
    const int k0 = kk * 64;
    bf16x8 av[4], bv[2];
#pragma unroll
    for (int i = 0; i < 4; ++i)
      av[i] = *(const bf16x8*)&A[(size_t)(m0 + srow + i * 8) * 512 + k0 + scol];
#pragma unroll
    for (int i = 0; i < 2; ++i)
      bv[i] = *(const bf16x8*)&WoutT[(size_t)(co0 + brow) * 512 + k0 + bcol + i * 8];
#pragma unroll
    for (int i = 0; i < 4; ++i)
      *(bf16x8*)&As[(srow + i * 8) * 72 + scol] = av[i];
#pragma unroll
    for (int i = 0; i < 2; ++i)
      *(bf16x8*)&Bs[brow * 72 + bcol + i * 8] = bv[i];
    __syncthreads();
#pragma unroll
    for (int ks = 0; ks < 2; ++ks) {
      bf16x8 a[4], bb[2];
#pragma unroll
      for (int rb = 0; rb < 4; ++rb)
        a[rb] = *(const bf16x8*)&As[(wr * 64 + rb * 16 + l16) * 72 + ks * 32 + quad * 8];
#pragma unroll
      for (int cb = 0; cb < 2; ++cb)
        bb[cb] = *(const bf16x8*)&Bs[(wc * 32 + cb * 16 + l16) * 72 + ks * 32 + quad * 8];
#pragma unroll
      for (int rb = 0; rb < 4; ++rb)
#pragma unroll
        for (int cb = 0; cb < 2; ++cb)
          acc[rb][cb] = __builtin_amdgcn_mfma_f32_16x16x32_bf16(a[rb], bb[cb], acc[rb][cb], 0, 0, 0);
    }
    __syncthreads();
  }

#pragma unroll
  for (int cb = 0; cb < 2; ++cb) {
    const int c = co0 + wc * 32 + cb * 16 + l16;
    const float bias = bout[c];
#pragma unroll
    for (int rb = 0; rb < 4; ++rb) {
      const int n = m0 + wr * 64 + rb * 16 + quad * 4;
      const size_t off = ((size_t)b * 512 + c) * 1024 + n;
      f32x4 res = *(const f32x4*)&x[off];
      f32x4 v = acc[rb][cb];
      f32x4 ov;
#pragma unroll
      for (int r = 0; r < 4; ++r) ov[r] = v[r] + bias + res[r];
      *(f32x4*)&out[off] = ov;
    }
  }
}

extern "C" void kernel_launch(void* const* d_in, const int* in_sizes, int n_in,
                              void* d_out, int out_size, void* d_ws, size_t ws_size,
                              hipStream_t stream) {
  const float* x = (const float*)d_in[0];     // [8][512][1024] fp32
  const float* Wqkv = (const float*)d_in[1];  // [512][1536]
  const float* bqkv = (const float*)d_in[2];  // [1536]
  const float* Wout = (const float*)d_in[3];  // [512][512]
  const float* bout = (const float*)d_in[4];  // [512]
  float* out = (float*)d_out;                 // [8][512][1024]
  char* ws = (char*)d_ws;

  const size_t MB = 1024 * 1024;
  bf16* xT = (bf16*)(ws);             // 8 MB [8][1024][512] bf16
  bf16* Ob = xT;                      // alias: xT dead after gemm_qkv
  bf16* Qbuf = (bf16*)(ws + 8 * MB);  // 8 MB [64][1024][64] (pre-scaled)
  bf16* Kbuf = (bf16*)(ws + 16 * MB); // 8 MB [64][1024][64]
  bf16* Vbuf = (bf16*)(ws + 24 * MB); // 8 MB [64][64][1024] d-major
  bf16* WqkvT = (bf16*)(ws + 32 * MB);            // 1.5 MB [1536][512]
  bf16* WoutT = (bf16*)(ws + 32 * MB + 1572864);  // 0.5 MB [512][512]
  if (ws_size < 32 * MB + 1572864 + 524288) return;

  prep_all<<<dim3(48, 16, 10), dim3(32, 8), 0, stream>>>(x, Wqkv, Wout, xT, WqkvT, WoutT);
  gemm_qkv<<<dim3(24, 8, 8), 256, 0, stream>>>(xT, WqkvT, bqkv, Qbuf, Kbuf, Vbuf);
  attn_k<<<dim3(64, 8), 256, 0, stream>>>(Qbuf, Kbuf, Vbuf, Ob);
  gemm_out<<<dim3(8, 8, 8), 256, 0, stream>>>(Ob, WoutT, bout, x, out);
}